// Round 9
// baseline (804.654 us; speedup 1.0000x reference)
//
#include <hip/hip_runtime.h>

typedef unsigned int u32;

#define B_ROWS 32768
#define EPS_BN 1e-5f

// GENUINE numpy-fp32 emulation — contraction disabled so these are the real bits:
//   sp = RN(RN(px^2)+RN(py^2)); sm = RN(RN(mx^2)+RN(my^2))   [no fma — enforced]
//   dot = fma(py,my, RN(px*mx))                              [OpenBLAS K-ascending FMA]
//   d2 = RN(RN(sp+sm) - 2*dot)                               [2*dot exact]
__device__ __forceinline__ float dcalc(float px, float py, float sp, float mx, float my) {
#pragma clang fp contract(off)
  float sm   = mx * mx + my * my;
  float pm   = px * mx;
  float dot  = __builtin_fmaf(py, my, pm);
  float spsm = sp + sm;
  return spsm - 2.0f * dot;
}
__device__ __forceinline__ float spcalc(float px, float py) {
#pragma clang fp contract(off)
  return px * px + py * py;
}

// ---------- KNN: 4 threads/query; med3-chain top-16, stable asc (d,idx) order ----------
__global__ __launch_bounds__(256)
void knn_kernel(const float2* __restrict__ pos, const float2* __restrict__ mc,
                const float2* __restrict__ mv, float* __restrict__ knn_out,
                float* __restrict__ X0)
{
  __shared__ int   bufI[256 * 24];    // 24 KB candidate store
  __shared__ float sD[256 * 16];      // 16 KB
  __shared__ int   sI[256 * 16];      // 16 KB

  const int t = threadIdx.x;
  const int lane = t & 63;
  const int slice = __builtin_amdgcn_readfirstlane(t >> 6);
  const int q = blockIdx.x * 64 + lane;
  const float2 p = pos[q];
  const float sp = spcalc(p.x, p.y);
  const int base = slice * 2048;

  // pass 1: branch-free top-16 VALUES via two interleaved med3 chains
  float dA[16], dB[16];
#pragma unroll
  for (int j = 0; j < 16; ++j) { dA[j] = __builtin_inff(); dB[j] = __builtin_inff(); }

  for (int i = 0; i < 2048; i += 2) {
    float2 m0 = mc[base + i];
    float2 m1 = mc[base + i + 1];
    float d0 = dcalc(p.x, p.y, sp, m0.x, m0.y);
    float d1 = dcalc(p.x, p.y, sp, m1.x, m1.y);
#pragma unroll
    for (int j = 15; j >= 1; --j) dA[j] = __builtin_amdgcn_fmed3f(dA[j-1], d0, dA[j]);
    dA[0] = fminf(dA[0], d0);
#pragma unroll
    for (int j = 15; j >= 1; --j) dB[j] = __builtin_amdgcn_fmed3f(dB[j-1], d1, dB[j]);
    dB[0] = fminf(dB[0], d1);
  }
  // exact 16th smallest VALUE of union of two sorted 16-lists
  float T = fminf(dA[15], dB[15]);
#pragma unroll
  for (int k = 1; k <= 15; ++k) T = fminf(T, fmaxf(dA[k-1], dB[15-k]));

  // pass 2: collect candidates with d <= T (identical rounding as pass 1)
  int cnt = 0;
  for (int i = 0; i < 2048; ++i) {
    float2 m = mc[base + i];
    float d = dcalc(p.x, p.y, sp, m.x, m.y);
    if (d <= T) {
      if (cnt < 24) bufI[t * 24 + cnt] = base + i;
      ++cnt;
    }
  }
  if (cnt > 24) cnt = 24;

  // per-slice stable-sorted (d asc, idx asc on ties) top-16
  float fd[16]; int fi[16];
#pragma unroll
  for (int j = 0; j < 16; ++j) { fd[j] = __builtin_inff(); fi[j] = 0; }
  for (int j = 0; j < cnt; ++j) {
    int ci = bufI[t * 24 + j];
    float2 m = mc[ci];
    float d = dcalc(p.x, p.y, sp, m.x, m.y);
    if (d < fd[15]) {                 // strict <: equal d keeps earlier (lower) index
      bool c = true;
#pragma unroll
      for (int s = 15; s >= 1; --s) {
        bool cm = d < fd[s-1];
        if (c) {
          if (cm) { fd[s] = fd[s-1]; fi[s] = fi[s-1]; }
          else    { fd[s] = d;       fi[s] = ci;      }
        }
        c = cm;
      }
      if (c) { fd[0] = d; fi[0] = ci; }
    }
  }
#pragma unroll
  for (int j = 0; j < 16; ++j) { sD[t*16 + j] = fd[j]; sI[t*16 + j] = fi[j]; }
  __syncthreads();

  // 4-way merge per query (wave 0); lower slice (lower indices) wins ties
  if (t < 64) {
    const int b0 = (0*64 + t) * 16, b1 = (1*64 + t) * 16;
    const int b2 = (2*64 + t) * 16, b3 = (3*64 + t) * 16;
    int h0 = 0, h1 = 0, h2 = 0, h3 = 0;
    float v0 = sD[b0], v1 = sD[b1], v2 = sD[b2], v3 = sD[b3];
    int sel[16];
#pragma unroll
    for (int j = 0; j < 16; ++j) {
      float best = v0; int bs = 0;
      if (v1 < best) { best = v1; bs = 1; }
      if (v2 < best) { best = v2; bs = 2; }
      if (v3 < best) { best = v3; bs = 3; }
      int hsel = (bs == 0) ? h0 : ((bs == 1) ? h1 : ((bs == 2) ? h2 : h3));
      int lb   = (bs == 0) ? b0 : ((bs == 1) ? b1 : ((bs == 2) ? b2 : b3));
      sel[j] = sI[lb + hsel];
      int hn = hsel + 1;
      float nv = (hn < 16) ? sD[lb + hn] : __builtin_inff();
      if (bs == 0) { h0 = hn; v0 = nv; }
      else if (bs == 1) { h1 = hn; v1 = nv; }
      else if (bs == 2) { h2 = hn; v2 = nv; }
      else { h3 = hn; v3 = nv; }
    }
    const int qq = blockIdx.x * 64 + t;
    float* orow = knn_out + (size_t)qq * 66;
    float* xrow = X0 + (size_t)qq * 96;
    float2 pp = pos[qq];
    orow[0] = pp.x; orow[1] = pp.y;
    xrow[0] = pp.x; xrow[1] = pp.y;
#pragma unroll
    for (int j = 0; j < 16; ++j) {
      int ci = sel[j];
      float2 m = mc[ci], v = mv[ci];
      orow[2 + 4*j + 0] = m.x; orow[2 + 4*j + 1] = m.y;
      orow[2 + 4*j + 2] = v.x; orow[2 + 4*j + 3] = v.y;
      xrow[2 + 4*j + 0] = m.x; xrow[2 + 4*j + 1] = m.y;
      xrow[2 + 4*j + 2] = v.x; xrow[2 + 4*j + 3] = v.y;
    }
#pragma unroll
    for (int c = 66; c < 96; ++c) xrow[c] = 0.0f;   // zero pad to Kpad=96
  }
}

// ---------- fp32 GEMM (vector FMA) + bias + column sum/sum^2 stats ----------
template<int BN>
__global__ __launch_bounds__(256)
void gemm_bn_f32(const float* __restrict__ X, int Kw, int Ktrue,
                 const float* __restrict__ W,
                 const float* __restrict__ bias,
                 float* __restrict__ Z, int N,
                 float* __restrict__ csum, float* __restrict__ csq)
{
  constexpr int BM  = 128;
  constexpr int KT  = 16;
  constexpr int AST = 132;
  constexpr int BNT = BN / 16;
  __shared__ float Ash[KT * AST];     // [k][row]
  __shared__ float Bsh[KT * BN];      // [k][n]
  __shared__ float redS[16 * BN];
  __shared__ float redQ[16 * BN];

  const int t  = threadIdx.x;
  const int tc = t & 15;
  const int tr = t >> 4;
  const int m0 = blockIdx.x * BM;
  const int n0 = blockIdx.y * BN;

  float acc[8][BNT];
#pragma unroll
  for (int i = 0; i < 8; ++i)
#pragma unroll
    for (int j = 0; j < BNT; ++j) acc[i][j] = 0.0f;

  for (int k0 = 0; k0 < Kw; k0 += KT) {
    {
      const int r  = t >> 2;
      const int kc = (t & 3) * 4;
#pragma unroll
      for (int rr = 0; rr < 2; ++rr) {
        const int row = r + rr * 64;
        float4 g = *(const float4*)(&X[(size_t)(m0 + row) * Kw + k0 + kc]);
        Ash[(kc+0)*AST + row] = g.x;
        Ash[(kc+1)*AST + row] = g.y;
        Ash[(kc+2)*AST + row] = g.z;
        Ash[(kc+3)*AST + row] = g.w;
      }
    }
    if (BN == 128) {
      const int kb = t >> 5;
      const int n  = (t & 31) * 4;
#pragma unroll
      for (int kk = 0; kk < 2; ++kk) {
        const int kr = kb + kk * 8;
        const int kg = k0 + kr;
        float4 g = make_float4(0.f, 0.f, 0.f, 0.f);
        if (kg < Ktrue) g = *(const float4*)(&W[(size_t)kg * N + n0 + n]);
        *(float4*)(&Bsh[kr * BN + n]) = g;
      }
    } else {
      const int kb = t >> 4;
      const int n  = (t & 15) * 4;
      const int kg = k0 + kb;
      float4 g = make_float4(0.f, 0.f, 0.f, 0.f);
      if (kg < Ktrue) g = *(const float4*)(&W[(size_t)kg * N + n0 + n]);
      *(float4*)(&Bsh[kb * BN + n]) = g;
    }
    __syncthreads();

#pragma unroll
    for (int k = 0; k < KT; ++k) {
      float a[8], b[BNT];
      *(float4*)&a[0] = *(const float4*)(&Ash[k * AST + tr * 8]);
      *(float4*)&a[4] = *(const float4*)(&Ash[k * AST + tr * 8 + 4]);
#pragma unroll
      for (int j = 0; j < BNT; j += 4)
        *(float4*)&b[j] = *(const float4*)(&Bsh[k * BN + tc * BNT + j]);
#pragma unroll
      for (int i = 0; i < 8; ++i)
#pragma unroll
        for (int j = 0; j < BNT; ++j)
          acc[i][j] = __fmaf_rn(a[i], b[j], acc[i][j]);
    }
    __syncthreads();
  }

  float bv[BNT], s[BNT], sq[BNT];
#pragma unroll
  for (int j = 0; j < BNT; ++j) {
    bv[j] = bias[n0 + tc * BNT + j];
    s[j] = 0.0f; sq[j] = 0.0f;
  }
#pragma unroll
  for (int i = 0; i < 8; ++i) {
    const int row = m0 + tr * 8 + i;
    float z[BNT];
#pragma unroll
    for (int j = 0; j < BNT; ++j) {
      z[j] = acc[i][j] + bv[j];
      s[j] += z[j];
      sq[j] = __fmaf_rn(z[j], z[j], sq[j]);
    }
#pragma unroll
    for (int j = 0; j < BNT; j += 4)
      *(float4*)(&Z[(size_t)row * N + n0 + tc * BNT + j]) = *(float4*)&z[j];
  }
#pragma unroll
  for (int j = 0; j < BNT; ++j) {
    redS[tr * BN + tc * BNT + j] = s[j];
    redQ[tr * BN + tc * BNT + j] = sq[j];
  }
  __syncthreads();
  if (t < BN) {
    float ss = 0.0f, qq = 0.0f;
#pragma unroll
    for (int g = 0; g < 16; ++g) { ss += redS[g * BN + t]; qq += redQ[g * BN + t]; }
    atomicAdd(&csum[n0 + t], ss);
    atomicAdd(&csq[n0 + t], qq);
  }
}

// ---------- BN (training stats) + ReLU, fp32 in-place ----------
__global__ __launch_bounds__(256)
void bnrelu_f32(float* __restrict__ Z, int N,
                const float* __restrict__ csum, const float* __restrict__ csq,
                const float* __restrict__ gw, const float* __restrict__ bw)
{
  const int i4 = blockIdx.x * 256 + threadIdx.x;
  float4 z = ((const float4*)Z)[i4];
  const int c0 = (i4 * 4) & (N - 1);
  const float invB = 1.0f / 32768.0f;
  float zz[4] = {z.x, z.y, z.z, z.w};
#pragma unroll
  for (int u = 0; u < 4; ++u) {
    const int c = c0 + u;
    float mean = csum[c] * invB;
    float var  = __fmaf_rn(-mean, mean, csq[c] * invB);
    float sc   = gw[c] * rsqrtf(var + EPS_BN);
    float tt   = __fmaf_rn(-mean, sc, bw[c]);
    zz[u] = fmaxf(__fmaf_rn(zz[u], sc, tt), 0.0f);
  }
  float4 o; o.x = zz[0]; o.y = zz[1]; o.z = zz[2]; o.w = zz[3];
  ((float4*)Z)[i4] = o;
}

// ---------- final 64->2 layer, fp32 ----------
__global__ __launch_bounds__(256)
void gemv6_f32(const float* __restrict__ X5, const float* __restrict__ w6,
               const float* __restrict__ b6, float* __restrict__ out)
{
  __shared__ float wsh[128];
  const int t = threadIdx.x;
  if (t < 128) wsh[t] = w6[t];
  __syncthreads();
  const int q = blockIdx.x * 256 + t;
  const float4* xv = (const float4*)(X5 + (size_t)q * 64);
  float a0 = 0.f, a1 = 0.f;
#pragma unroll
  for (int cc = 0; cc < 16; ++cc) {
    float4 x = xv[cc];
    float xs[4] = {x.x, x.y, x.z, x.w};
#pragma unroll
    for (int u = 0; u < 4; ++u) {
      const int k = cc * 4 + u;
      a0 = __fmaf_rn(xs[u], wsh[2 * k + 0], a0);
      a1 = __fmaf_rn(xs[u], wsh[2 * k + 1], a1);
    }
  }
  float2 o; o.x = a0 + b6[0]; o.y = a1 + b6[1];
  ((float2*)out)[q] = o;
}

// ---------- launch ----------
extern "C" void kernel_launch(void* const* d_in, const int* in_sizes, int n_in,
                              void* d_out, int out_size, void* d_ws, size_t ws_size,
                              hipStream_t stream)
{
  const float2* pos = (const float2*)d_in[0];
  const float2* mc  = (const float2*)d_in[1];
  const float2* mv  = (const float2*)d_in[2];
  const float* w1 = (const float*)d_in[3];  const float* b1 = (const float*)d_in[4];
  const float* w2 = (const float*)d_in[5];  const float* b2 = (const float*)d_in[6];
  const float* w3 = (const float*)d_in[7];  const float* b3 = (const float*)d_in[8];
  const float* w4 = (const float*)d_in[9];  const float* b4 = (const float*)d_in[10];
  const float* w5 = (const float*)d_in[11]; const float* b5 = (const float*)d_in[12];
  const float* w6 = (const float*)d_in[13]; const float* b6 = (const float*)d_in[14];
  const float* g1 = (const float*)d_in[15]; const float* be1 = (const float*)d_in[16];
  const float* g2 = (const float*)d_in[17]; const float* be2 = (const float*)d_in[18];
  const float* g3 = (const float*)d_in[19]; const float* be3 = (const float*)d_in[20];
  const float* g4 = (const float*)d_in[21]; const float* be4 = (const float*)d_in[22];
  const float* g5 = (const float*)d_in[23]; const float* be5 = (const float*)d_in[24];

  // ws layout (fp32): P0 12.58MB | PA 67.11MB | PB 33.55MB | stats
  char* ws = (char*)d_ws;
  float* P0 = (float*)(ws + 0);
  float* PA = (float*)(ws + 12582912);
  float* PB = (float*)(ws + 79691776);
  float* stats = (float*)(ws + 113246208);
  float* s1 = stats;        float* s2 = stats + 128;  float* s3 = stats + 384;
  float* s4 = stats + 896;  float* s5 = stats + 1024;
  float* sqb = stats + 1088;
  float* q1 = sqb;          float* q2 = sqb + 128;    float* q3 = sqb + 384;
  float* q4 = sqb + 896;    float* q5 = sqb + 1024;

  float* outX = (float*)d_out;
  float* outK = outX + 2 * B_ROWS;

  hipMemsetAsync(stats, 0, 2176 * sizeof(float), stream);
  knn_kernel<<<dim3(512), 256, 0, stream>>>(pos, mc, mv, outK, P0);

  gemm_bn_f32<128><<<dim3(256, 1), 256, 0, stream>>>(P0, 96, 66, w1, b1, PA, 128, s1, q1);
  bnrelu_f32<<<dim3(4096), 256, 0, stream>>>(PA, 128, s1, q1, g1, be1);
  gemm_bn_f32<128><<<dim3(256, 2), 256, 0, stream>>>(PA, 128, 128, w2, b2, PB, 256, s2, q2);
  bnrelu_f32<<<dim3(8192), 256, 0, stream>>>(PB, 256, s2, q2, g2, be2);
  gemm_bn_f32<128><<<dim3(256, 4), 256, 0, stream>>>(PB, 256, 256, w3, b3, PA, 512, s3, q3);
  bnrelu_f32<<<dim3(16384), 256, 0, stream>>>(PA, 512, s3, q3, g3, be3);
  gemm_bn_f32<128><<<dim3(256, 1), 256, 0, stream>>>(PA, 512, 512, w4, b4, PB, 128, s4, q4);
  bnrelu_f32<<<dim3(4096), 256, 0, stream>>>(PB, 128, s4, q4, g4, be4);
  gemm_bn_f32<64><<<dim3(256, 1), 256, 0, stream>>>(PB, 128, 128, w5, b5, PA, 64, s5, q5);
  bnrelu_f32<<<dim3(2048), 256, 0, stream>>>(PA, 64, s5, q5, g5, be5);
  gemv6_f32<<<dim3(128), 256, 0, stream>>>(PA, w6, b6, outX);

  (void)in_sizes; (void)n_in; (void)out_size; (void)ws_size;
}

// Round 10
// 587.520 us; speedup vs baseline: 1.3696x; 1.3696x over previous
//
#include <hip/hip_runtime.h>

typedef unsigned short u16;
typedef unsigned int   u32;
typedef __attribute__((ext_vector_type(8))) short bf16x8;
typedef __attribute__((ext_vector_type(4))) float f32x4;

#define B_ROWS 32768
#define EPS_BN 1e-5f

// ---------- helpers ----------
__device__ __forceinline__ u16 f2bf(float f) {
  u32 u = __float_as_uint(f);
  u32 r = (u + 0x7FFFu + ((u >> 16) & 1u)) >> 16;   // RNE, no NaN inputs
  return (u16)r;
}
__device__ __forceinline__ float bf2f(u16 h) {
  return __uint_as_float(((u32)h) << 16);
}

// GENUINE numpy-fp32 emulation — contraction disabled (THE critical fix, R9):
//   sp = RN(RN(px^2)+RN(py^2)); sm = RN(RN(mx^2)+RN(my^2))   [no fma]
//   dot = fma(py,my, RN(px*mx));  d2 = RN(RN(sp+sm) - 2*dot)
__device__ __forceinline__ float dcalc(float px, float py, float sp, float mx, float my) {
#pragma clang fp contract(off)
  float sm   = mx * mx + my * my;
  float pm   = px * mx;
  float dot  = __builtin_fmaf(py, my, pm);
  float spsm = sp + sm;
  return spsm - 2.0f * dot;
}
__device__ __forceinline__ float spcalc(float px, float py) {
#pragma clang fp contract(off)
  return px * px + py * py;
}

// ---------- KNN: 4 threads/query; med3-chain top-16, stable asc (d,idx) ----------
// LDS: single 32 KB region, phase-overlaid (bufI[256][32] -> sD[4096]f | sI[4096]i)
__global__ __launch_bounds__(256, 5)
void knn_kernel(const float2* __restrict__ pos, const float2* __restrict__ mc,
                const float2* __restrict__ mv, float* __restrict__ knn_out,
                u16* __restrict__ X0)
{
  __shared__ int uni[8192];           // 32 KB

  const int t = threadIdx.x;
  const int lane = t & 63;
  const int slice = __builtin_amdgcn_readfirstlane(t >> 6);
  const int q = blockIdx.x * 64 + lane;
  const float2 p = pos[q];
  const float sp = spcalc(p.x, p.y);
  const int base = slice * 2048;               // point index
  const float4* mc4 = (const float4*)mc;       // 2 points per float4
  const int b4 = slice * 1024;

  // pass 1: branch-free top-16 VALUES via two interleaved med3 chains
  float dA[16], dB[16];
#pragma unroll
  for (int j = 0; j < 16; ++j) { dA[j] = __builtin_inff(); dB[j] = __builtin_inff(); }

  float4 cur = mc4[b4];
  for (int i = 0; i < 1024; ++i) {
    float4 nxt = mc4[b4 + ((i + 1) & 1023)];   // depth-1 prefetch (wraps, harmless)
    float d0 = dcalc(p.x, p.y, sp, cur.x, cur.y);
    float d1 = dcalc(p.x, p.y, sp, cur.z, cur.w);
#pragma unroll
    for (int j = 15; j >= 1; --j) dA[j] = __builtin_amdgcn_fmed3f(dA[j-1], d0, dA[j]);
    dA[0] = fminf(dA[0], d0);
#pragma unroll
    for (int j = 15; j >= 1; --j) dB[j] = __builtin_amdgcn_fmed3f(dB[j-1], d1, dB[j]);
    dB[0] = fminf(dB[0], d1);
    cur = nxt;
  }
  // exact 16th smallest of union of two sorted 16-lists
  float T = fminf(dA[15], dB[15]);
#pragma unroll
  for (int k = 1; k <= 15; ++k) T = fminf(T, fmaxf(dA[k-1], dB[15-k]));

  // pass 2: collect candidates with d <= T into bufI (= uni[t*32 ..])
  int cnt = 0;
  for (int i = 0; i < 1024; ++i) {
    float4 c2 = mc4[b4 + i];
    float d0 = dcalc(p.x, p.y, sp, c2.x, c2.y);
    float d1 = dcalc(p.x, p.y, sp, c2.z, c2.w);
    if (d0 <= T) { if (cnt < 32) uni[t * 32 + cnt] = base + 2 * i;     ++cnt; }
    if (d1 <= T) { if (cnt < 32) uni[t * 32 + cnt] = base + 2 * i + 1; ++cnt; }
  }
  if (cnt > 32) cnt = 32;

  // per-slice stable-sorted (d asc, idx asc on ties) top-16 (reads own bufI)
  float fd[16]; int fi[16];
#pragma unroll
  for (int j = 0; j < 16; ++j) { fd[j] = __builtin_inff(); fi[j] = 0; }
  for (int j = 0; j < cnt; ++j) {
    int ci = uni[t * 32 + j];
    float2 m = mc[ci];
    float d = dcalc(p.x, p.y, sp, m.x, m.y);
    if (d < fd[15]) {                 // strict <: equal d keeps earlier (lower) index
      bool c = true;
#pragma unroll
      for (int s = 15; s >= 1; --s) {
        bool cm = d < fd[s-1];
        if (c) {
          if (cm) { fd[s] = fd[s-1]; fi[s] = fi[s-1]; }
          else    { fd[s] = d;       fi[s] = ci;      }
        }
        c = cm;
      }
      if (c) { fd[0] = d; fi[0] = ci; }
    }
  }
  __syncthreads();                    // all bufI reads done before overlay reuse

  float* sD = (float*)uni;            // first 16 KB
  int*   sI = uni + 4096;             // second 16 KB
#pragma unroll
  for (int j = 0; j < 16; ++j) { sD[t*16 + j] = fd[j]; sI[t*16 + j] = fi[j]; }
  __syncthreads();

  // 4-way merge per query (wave 0); lower slice (lower indices) wins ties
  if (t < 64) {
    const int b0 = (0*64 + t) * 16, b1 = (1*64 + t) * 16;
    const int b2 = (2*64 + t) * 16, b3 = (3*64 + t) * 16;
    int h0 = 0, h1 = 0, h2 = 0, h3 = 0;
    float v0 = sD[b0], v1 = sD[b1], v2 = sD[b2], v3 = sD[b3];
    int sel[16];
#pragma unroll
    for (int j = 0; j < 16; ++j) {
      float best = v0; int bs = 0;
      if (v1 < best) { best = v1; bs = 1; }
      if (v2 < best) { best = v2; bs = 2; }
      if (v3 < best) { best = v3; bs = 3; }
      int hsel = (bs == 0) ? h0 : ((bs == 1) ? h1 : ((bs == 2) ? h2 : h3));
      int lb   = (bs == 0) ? b0 : ((bs == 1) ? b1 : ((bs == 2) ? b2 : b3));
      sel[j] = sI[lb + hsel];
      int hn = hsel + 1;
      float nv = (hn < 16) ? sD[lb + hn] : __builtin_inff();
      if (bs == 0) { h0 = hn; v0 = nv; }
      else if (bs == 1) { h1 = hn; v1 = nv; }
      else if (bs == 2) { h2 = hn; v2 = nv; }
      else { h3 = hn; v3 = nv; }
    }
    const int qq = blockIdx.x * 64 + t;
    float* orow = knn_out + (size_t)qq * 66;   // fp32 output 1 (knn_feat)
    u16*   xrow = X0 + (size_t)qq * 96;        // bf16 MLP input, Kpad=96
    float2 pp = pos[qq];
    orow[0] = pp.x; orow[1] = pp.y;
    xrow[0] = f2bf(pp.x); xrow[1] = f2bf(pp.y);
#pragma unroll
    for (int j = 0; j < 16; ++j) {
      int ci = sel[j];
      float2 m = mc[ci], v = mv[ci];
      orow[2 + 4*j + 0] = m.x; orow[2 + 4*j + 1] = m.y;
      orow[2 + 4*j + 2] = v.x; orow[2 + 4*j + 3] = v.y;
      xrow[2 + 4*j + 0] = f2bf(m.x); xrow[2 + 4*j + 1] = f2bf(m.y);
      xrow[2 + 4*j + 2] = f2bf(v.x); xrow[2 + 4*j + 3] = f2bf(v.y);
    }
#pragma unroll
    for (int c = 66; c < 96; ++c) xrow[c] = 0;
  }
}

// ---------- weight prep: fp32 [K][N] -> bf16 transposed [N][Kpad] (zero-padded) ----------
__global__ __launch_bounds__(256)
void prep_wt_all(const float* __restrict__ w1, const float* __restrict__ w2,
                 const float* __restrict__ w3, const float* __restrict__ w4,
                 const float* __restrict__ w5,
                 u16* __restrict__ wt1, u16* __restrict__ wt2, u16* __restrict__ wt3,
                 u16* __restrict__ wt4, u16* __restrict__ wt5)
{
  const int l = blockIdx.y;
  const float* w; u16* wt; int K, N, Kp;
  if (l == 0)      { w = w1; wt = wt1; K = 66;  N = 128; Kp = 96;  }
  else if (l == 1) { w = w2; wt = wt2; K = 128; N = 256; Kp = 128; }
  else if (l == 2) { w = w3; wt = wt3; K = 256; N = 512; Kp = 256; }
  else if (l == 3) { w = w4; wt = wt4; K = 512; N = 128; Kp = 512; }
  else             { w = w5; wt = wt5; K = 128; N = 64;  Kp = 128; }
  int i = blockIdx.x * 256 + threadIdx.x;
  if (i >= N * Kp) return;
  int n = i / Kp, kp = i - n * Kp;
  float v = (kp < K) ? w[(size_t)kp * N + n] : 0.0f;
  wt[i] = f2bf(v);
}

// ---------- GEMM (bf16 MFMA 16x16x32) + bias + column sum/sum^2 stats ----------
template<int BN>
__global__ __launch_bounds__(256)
void gemm_bn_kernel(const u16* __restrict__ X, int Kw,
                    const u16* __restrict__ WT,
                    const float* __restrict__ bias,
                    u16* __restrict__ Z, int N,
                    float* __restrict__ csum, float* __restrict__ csq)
{
  constexpr int BM = 128;
  constexpr int AST = 40;                 // 32 data + 8 pad (bf16), rows 80B
  __shared__ u16 Ash[BM * AST];
  __shared__ u16 Bsh[BN * AST];
  __shared__ float redS[4][128];
  __shared__ float redQ[4][128];

  const int t = threadIdx.x;
  const int wave = t >> 6;
  const int lane = t & 63;
  const int lr = lane & 15;
  const int qd = lane >> 4;
  const int m0 = blockIdx.x * BM;
  const int n0 = blockIdx.y * BN;

  f32x4 acc[2][BN / 16];
#pragma unroll
  for (int a = 0; a < 2; ++a)
#pragma unroll
    for (int b = 0; b < BN / 16; ++b) {
      acc[a][b][0] = 0.f; acc[a][b][1] = 0.f; acc[a][b][2] = 0.f; acc[a][b][3] = 0.f;
    }

  const int sr = t >> 2;          // 0..63
  const int sk = (t & 3) * 8;     // 0,8,16,24

  for (int k0 = 0; k0 < Kw; k0 += 32) {
#pragma unroll
    for (int rr = 0; rr < 2; ++rr) {
      int r = sr + rr * 64;
      *(uint4*)(&Ash[r * AST + sk]) =
          *(const uint4*)(&X[(size_t)(m0 + r) * Kw + k0 + sk]);
    }
#pragma unroll
    for (int rr = 0; rr < BN / 64; ++rr) {
      int n = sr + rr * 64;
      *(uint4*)(&Bsh[n * AST + sk]) =
          *(const uint4*)(&WT[(size_t)(n0 + n) * Kw + k0 + sk]);
    }
    __syncthreads();
    bf16x8 af0 = *(const bf16x8*)(&Ash[(wave * 32 + lr) * AST + qd * 8]);
    bf16x8 af1 = *(const bf16x8*)(&Ash[(wave * 32 + 16 + lr) * AST + qd * 8]);
#pragma unroll
    for (int ct = 0; ct < BN / 16; ++ct) {
      bf16x8 bfr = *(const bf16x8*)(&Bsh[(ct * 16 + lr) * AST + qd * 8]);
      acc[0][ct] = __builtin_amdgcn_mfma_f32_16x16x32_bf16(af0, bfr, acc[0][ct], 0, 0, 0);
      acc[1][ct] = __builtin_amdgcn_mfma_f32_16x16x32_bf16(af1, bfr, acc[1][ct], 0, 0, 0);
    }
    __syncthreads();
  }

  // epilogue: bias, bf16 Z store, per-column partial sums
#pragma unroll
  for (int ct = 0; ct < BN / 16; ++ct) {
    int cg = n0 + ct * 16 + lr;
    float bv = bias[cg];
    float s = 0.f, sqv = 0.f;
#pragma unroll
    for (int rt = 0; rt < 2; ++rt) {
#pragma unroll
      for (int r = 0; r < 4; ++r) {
        float z = acc[rt][ct][r] + bv;
        int row = m0 + wave * 32 + rt * 16 + qd * 4 + r;  // C/D: row=quad*4+reg, col=lane&15
        Z[(size_t)row * N + cg] = f2bf(z);
        s += z;
        sqv = __fmaf_rn(z, z, sqv);
      }
    }
    s   += __shfl_xor(s, 16);   s   += __shfl_xor(s, 32);
    sqv += __shfl_xor(sqv, 16); sqv += __shfl_xor(sqv, 32);
    if (qd == 0) { redS[wave][ct * 16 + lr] = s; redQ[wave][ct * 16 + lr] = sqv; }
  }
  __syncthreads();
  if (t < BN) {
    float s  = redS[0][t] + redS[1][t] + redS[2][t] + redS[3][t];
    float sv = redQ[0][t] + redQ[1][t] + redQ[2][t] + redQ[3][t];
    atomicAdd(&csum[n0 + t], s);
    atomicAdd(&csq[n0 + t], sv);
  }
}

// ---------- BN (training stats) + ReLU -> bf16 activations ----------
__global__ __launch_bounds__(256)
void bnrelu_kernel(const u16* __restrict__ Z, int N,
                   const float* __restrict__ csum, const float* __restrict__ csq,
                   const float* __restrict__ gw, const float* __restrict__ bw,
                   u16* __restrict__ Xn)
{
  const int i8 = blockIdx.x * 256 + threadIdx.x;     // 8 elements per thread
  uint4 zp = ((const uint4*)Z)[i8];
  const int c0 = (i8 * 8) & (N - 1);                 // N is a power of two
  u32 wv[4] = {zp.x, zp.y, zp.z, zp.w};
  const float invB = 1.0f / 32768.0f;
  u32 ov[4];
#pragma unroll
  for (int u = 0; u < 4; ++u) {
    u32 res = 0;
#pragma unroll
    for (int hl = 0; hl < 2; ++hl) {
      int c = c0 + 2 * u + hl;
      float zz = bf2f((u16)((wv[u] >> (16 * hl)) & 0xffffu));
      float mean = csum[c] * invB;
      float var  = __fmaf_rn(-mean, mean, csq[c] * invB);  // biased
      float s    = gw[c] * rsqrtf(var + EPS_BN);
      float tt   = __fmaf_rn(-mean, s, bw[c]);
      float y    = fmaxf(__fmaf_rn(zz, s, tt), 0.0f);
      res |= ((u32)f2bf(y)) << (16 * hl);
    }
    ov[u] = res;
  }
  uint4 o4; o4.x = ov[0]; o4.y = ov[1]; o4.z = ov[2]; o4.w = ov[3];
  ((uint4*)Xn)[i8] = o4;
}

// ---------- final 64->2 layer, bf16 in / fp32 out ----------
__global__ __launch_bounds__(256)
void gemv6_kernel(const u16* __restrict__ X5, const float* __restrict__ w6,
                  const float* __restrict__ b6, float* __restrict__ out)
{
  __shared__ float wsh[128];
  const int t = threadIdx.x;
  if (t < 128) wsh[t] = w6[t];
  __syncthreads();
  const int q = blockIdx.x * 256 + t;
  const uint4* xv = (const uint4*)(X5 + (size_t)q * 64);
  float a0 = 0.f, a1 = 0.f;
#pragma unroll
  for (int cc = 0; cc < 8; ++cc) {
    uint4 pk = xv[cc];
    u32 u[4] = {pk.x, pk.y, pk.z, pk.w};
#pragma unroll
    for (int uu = 0; uu < 4; ++uu) {
      float x0 = bf2f((u16)(u[uu] & 0xffffu));
      float x1 = bf2f((u16)(u[uu] >> 16));
      int k = cc * 8 + uu * 2;
      a0 = __fmaf_rn(x0, wsh[2 * k + 0], a0);
      a1 = __fmaf_rn(x0, wsh[2 * k + 1], a1);
      a0 = __fmaf_rn(x1, wsh[2 * k + 2], a0);
      a1 = __fmaf_rn(x1, wsh[2 * k + 3], a1);
    }
  }
  float2 o; o.x = a0 + b6[0]; o.y = a1 + b6[1];
  ((float2*)out)[q] = o;
}

// ---------- launch ----------
extern "C" void kernel_launch(void* const* d_in, const int* in_sizes, int n_in,
                              void* d_out, int out_size, void* d_ws, size_t ws_size,
                              hipStream_t stream)
{
  const float2* pos = (const float2*)d_in[0];
  const float2* mc  = (const float2*)d_in[1];
  const float2* mv  = (const float2*)d_in[2];
  const float* w1 = (const float*)d_in[3];  const float* b1 = (const float*)d_in[4];
  const float* w2 = (const float*)d_in[5];  const float* b2 = (const float*)d_in[6];
  const float* w3 = (const float*)d_in[7];  const float* b3 = (const float*)d_in[8];
  const float* w4 = (const float*)d_in[9];  const float* b4 = (const float*)d_in[10];
  const float* w5 = (const float*)d_in[11]; const float* b5 = (const float*)d_in[12];
  const float* w6 = (const float*)d_in[13]; const float* b6 = (const float*)d_in[14];
  const float* g1 = (const float*)d_in[15]; const float* be1 = (const float*)d_in[16];
  const float* g2 = (const float*)d_in[17]; const float* be2 = (const float*)d_in[18];
  const float* g3 = (const float*)d_in[19]; const float* be3 = (const float*)d_in[20];
  const float* g4 = (const float*)d_in[21]; const float* be4 = (const float*)d_in[22];
  const float* g5 = (const float*)d_in[23]; const float* be5 = (const float*)d_in[24];

  // ws layout (bf16): Z 33.55MB | XA 33.55MB | XB 33.55MB | WT1..5 | stats
  char* ws = (char*)d_ws;
  u16* Z    = (u16*)(ws + 0);
  u16* XA   = (u16*)(ws + 33554432);
  u16* XB   = (u16*)(ws + 67108864);
  u16* WT1  = (u16*)(ws + 100663296);
  u16* WT2  = (u16*)(ws + 100687872);
  u16* WT3  = (u16*)(ws + 100753408);
  u16* WT4  = (u16*)(ws + 101015552);
  u16* WT5  = (u16*)(ws + 101146624);
  float* stats = (float*)(ws + 101163008);
  float* s1 = stats;        float* s2 = stats + 128;  float* s3 = stats + 384;
  float* s4 = stats + 896;  float* s5 = stats + 1024;
  float* sqb = stats + 1088;
  float* q1 = sqb;          float* q2 = sqb + 128;    float* q3 = sqb + 384;
  float* q4 = sqb + 896;    float* q5 = sqb + 1024;

  float* outX = (float*)d_out;
  float* outK = outX + 2 * B_ROWS;

  hipMemsetAsync(stats, 0, 2176 * sizeof(float), stream);
  prep_wt_all<<<dim3(512, 5), 256, 0, stream>>>(w1, w2, w3, w4, w5, WT1, WT2, WT3, WT4, WT5);
  knn_kernel<<<dim3(512), 256, 0, stream>>>(pos, mc, mv, outK, XA);

  gemm_bn_kernel<128><<<dim3(256, 1), 256, 0, stream>>>(XA, 96,  WT1, b1, Z, 128, s1, q1);
  bnrelu_kernel<<<dim3(2048), 256, 0, stream>>>(Z, 128, s1, q1, g1, be1, XB);
  gemm_bn_kernel<128><<<dim3(256, 2), 256, 0, stream>>>(XB, 128, WT2, b2, Z, 256, s2, q2);
  bnrelu_kernel<<<dim3(4096), 256, 0, stream>>>(Z, 256, s2, q2, g2, be2, XA);
  gemm_bn_kernel<128><<<dim3(256, 4), 256, 0, stream>>>(XA, 256, WT3, b3, Z, 512, s3, q3);
  bnrelu_kernel<<<dim3(8192), 256, 0, stream>>>(Z, 512, s3, q3, g3, be3, XB);
  gemm_bn_kernel<128><<<dim3(256, 1), 256, 0, stream>>>(XB, 512, WT4, b4, Z, 128, s4, q4);
  bnrelu_kernel<<<dim3(2048), 256, 0, stream>>>(Z, 128, s4, q4, g4, be4, XA);
  gemm_bn_kernel<64><<<dim3(256, 1), 256, 0, stream>>>(XA, 128, WT5, b5, Z, 64, s5, q5);
  bnrelu_kernel<<<dim3(1024), 256, 0, stream>>>(Z, 64, s5, q5, g5, be5, XB);
  gemv6_kernel<<<dim3(128), 256, 0, stream>>>(XB, w6, b6, outX);

  (void)in_sizes; (void)n_in; (void)out_size; (void)ws_size;
}

// Round 11
// 530.318 us; speedup vs baseline: 1.5173x; 1.1079x over previous
//
#include <hip/hip_runtime.h>

typedef unsigned short u16;
typedef unsigned int   u32;
typedef __attribute__((ext_vector_type(8))) short bf16x8;
typedef __attribute__((ext_vector_type(4))) float f32x4;

#define B_ROWS 32768
#define EPS_BN 1e-5f

// ---------- helpers ----------
__device__ __forceinline__ u16 f2bf(float f) {
  u32 u = __float_as_uint(f);
  u32 r = (u + 0x7FFFu + ((u >> 16) & 1u)) >> 16;   // RNE, no NaN inputs
  return (u16)r;
}
__device__ __forceinline__ float bf2f(u16 h) {
  return __uint_as_float(((u32)h) << 16);
}

// GENUINE numpy-fp32 emulation — contraction disabled (critical fix, R9):
//   sp = RN(RN(px^2)+RN(py^2)); sm = RN(RN(mx^2)+RN(my^2))   [no fma]
//   dot = fma(py,my, RN(px*mx));  d2 = RN(RN(sp+sm) - 2*dot)
__device__ __forceinline__ float dcalc(float px, float py, float sp, float mx, float my) {
#pragma clang fp contract(off)
  float sm   = mx * mx + my * my;
  float pm   = px * mx;
  float dot  = __builtin_fmaf(py, my, pm);
  float spsm = sp + sm;
  return spsm - 2.0f * dot;
}
__device__ __forceinline__ float spcalc(float px, float py) {
#pragma clang fp contract(off)
  return px * px + py * py;
}

// ---------- KNN: 8 threads/query (1024 blocks -> ~4 blocks/CU) ----------
// med3-chain top-16 per slice, stable asc (d,idx); 8-way merge per query.
__global__ __launch_bounds__(256, 5)
void knn_kernel(const float2* __restrict__ pos, const float2* __restrict__ mc,
                const float2* __restrict__ mv, float* __restrict__ knn_out,
                u16* __restrict__ X0)
{
  __shared__ int uni[8192];           // 32 KB, phase-overlaid

  const int t = threadIdx.x;
  const int qloc = t & 31;                       // query within block
  const int slice = t >> 5;                      // 0..7
  const int q = blockIdx.x * 32 + qloc;
  const float2 p = pos[q];
  const float sp = spcalc(p.x, p.y);
  const int base = slice * 1024;                 // point index
  const float4* mc4 = (const float4*)mc;         // 2 points per float4
  const int b4 = slice * 512;

  // pass 1: branch-free top-16 VALUES via two interleaved med3 chains
  float dA[16], dB[16];
#pragma unroll
  for (int j = 0; j < 16; ++j) { dA[j] = __builtin_inff(); dB[j] = __builtin_inff(); }

  float4 cur = mc4[b4];
  for (int i = 0; i < 512; ++i) {
    float4 nxt = mc4[b4 + ((i + 1) & 511)];      // depth-1 prefetch
    float d0 = dcalc(p.x, p.y, sp, cur.x, cur.y);
    float d1 = dcalc(p.x, p.y, sp, cur.z, cur.w);
#pragma unroll
    for (int j = 15; j >= 1; --j) dA[j] = __builtin_amdgcn_fmed3f(dA[j-1], d0, dA[j]);
    dA[0] = fminf(dA[0], d0);
#pragma unroll
    for (int j = 15; j >= 1; --j) dB[j] = __builtin_amdgcn_fmed3f(dB[j-1], d1, dB[j]);
    dB[0] = fminf(dB[0], d1);
    cur = nxt;
  }
  // exact slice-local 16th smallest of union of two sorted 16-lists
  float T = fminf(dA[15], dB[15]);
#pragma unroll
  for (int k = 1; k <= 15; ++k) T = fminf(T, fmaxf(dA[k-1], dB[15-k]));

  // pass 2: collect candidates with d <= T into bufI (= uni[t*32 ..])
  int cnt = 0;
  for (int i = 0; i < 512; ++i) {
    float4 c2 = mc4[b4 + i];
    float d0 = dcalc(p.x, p.y, sp, c2.x, c2.y);
    float d1 = dcalc(p.x, p.y, sp, c2.z, c2.w);
    if (d0 <= T) { if (cnt < 32) uni[t * 32 + cnt] = base + 2 * i;     ++cnt; }
    if (d1 <= T) { if (cnt < 32) uni[t * 32 + cnt] = base + 2 * i + 1; ++cnt; }
  }
  if (cnt > 32) cnt = 32;

  // per-slice stable-sorted (d asc, idx asc on ties) top-16
  float fd[16]; int fi[16];
#pragma unroll
  for (int j = 0; j < 16; ++j) { fd[j] = __builtin_inff(); fi[j] = 0; }
  for (int j = 0; j < cnt; ++j) {
    int ci = uni[t * 32 + j];
    float2 m = mc[ci];
    float d = dcalc(p.x, p.y, sp, m.x, m.y);
    if (d < fd[15]) {                 // strict <: equal d keeps earlier (lower) index
      bool c = true;
#pragma unroll
      for (int s = 15; s >= 1; --s) {
        bool cm = d < fd[s-1];
        if (c) {
          if (cm) { fd[s] = fd[s-1]; fi[s] = fi[s-1]; }
          else    { fd[s] = d;       fi[s] = ci;      }
        }
        c = cm;
      }
      if (c) { fd[0] = d; fi[0] = ci; }
    }
  }
  __syncthreads();                    // bufI reads done before overlay reuse

  float* sD = (float*)uni;            // 16 KB
  int*   sI = uni + 4096;             // 16 KB
#pragma unroll
  for (int j = 0; j < 16; ++j) { sD[t*16 + j] = fd[j]; sI[t*16 + j] = fi[j]; }
  __syncthreads();

  // 8-way merge per query (threads 0..31); lower slice = lower indices wins ties
  if (t < 32) {
    int bb[8];
#pragma unroll
    for (int s = 0; s < 8; ++s) bb[s] = (s * 32 + t) * 16;
    int h0=0,h1=0,h2=0,h3=0,h4=0,h5=0,h6=0,h7=0;
    float v0=sD[bb[0]], v1=sD[bb[1]], v2=sD[bb[2]], v3=sD[bb[3]];
    float v4=sD[bb[4]], v5=sD[bb[5]], v6=sD[bb[6]], v7=sD[bb[7]];
    int sel[16];
#pragma unroll
    for (int j = 0; j < 16; ++j) {
      float best = v0; int bs = 0;
      if (v1 < best) { best = v1; bs = 1; }
      if (v2 < best) { best = v2; bs = 2; }
      if (v3 < best) { best = v3; bs = 3; }
      if (v4 < best) { best = v4; bs = 4; }
      if (v5 < best) { best = v5; bs = 5; }
      if (v6 < best) { best = v6; bs = 6; }
      if (v7 < best) { best = v7; bs = 7; }
      if      (bs == 0) { sel[j] = sI[bb[0]+h0]; ++h0; v0 = (h0<16)? sD[bb[0]+h0] : __builtin_inff(); }
      else if (bs == 1) { sel[j] = sI[bb[1]+h1]; ++h1; v1 = (h1<16)? sD[bb[1]+h1] : __builtin_inff(); }
      else if (bs == 2) { sel[j] = sI[bb[2]+h2]; ++h2; v2 = (h2<16)? sD[bb[2]+h2] : __builtin_inff(); }
      else if (bs == 3) { sel[j] = sI[bb[3]+h3]; ++h3; v3 = (h3<16)? sD[bb[3]+h3] : __builtin_inff(); }
      else if (bs == 4) { sel[j] = sI[bb[4]+h4]; ++h4; v4 = (h4<16)? sD[bb[4]+h4] : __builtin_inff(); }
      else if (bs == 5) { sel[j] = sI[bb[5]+h5]; ++h5; v5 = (h5<16)? sD[bb[5]+h5] : __builtin_inff(); }
      else if (bs == 6) { sel[j] = sI[bb[6]+h6]; ++h6; v6 = (h6<16)? sD[bb[6]+h6] : __builtin_inff(); }
      else              { sel[j] = sI[bb[7]+h7]; ++h7; v7 = (h7<16)? sD[bb[7]+h7] : __builtin_inff(); }
    }
    const int qq = blockIdx.x * 32 + t;
    float* orow = knn_out + (size_t)qq * 66;   // fp32 output 1 (knn_feat)
    u16*   xrow = X0 + (size_t)qq * 96;        // bf16 MLP input, Kpad=96
    float2 pp = pos[qq];
    orow[0] = pp.x; orow[1] = pp.y;
    xrow[0] = f2bf(pp.x); xrow[1] = f2bf(pp.y);
#pragma unroll
    for (int j = 0; j < 16; ++j) {
      int ci = sel[j];
      float2 m = mc[ci], v = mv[ci];
      orow[2 + 4*j + 0] = m.x; orow[2 + 4*j + 1] = m.y;
      orow[2 + 4*j + 2] = v.x; orow[2 + 4*j + 3] = v.y;
      xrow[2 + 4*j + 0] = f2bf(m.x); xrow[2 + 4*j + 1] = f2bf(m.y);
      xrow[2 + 4*j + 2] = f2bf(v.x); xrow[2 + 4*j + 3] = f2bf(v.y);
    }
#pragma unroll
    for (int c = 66; c < 96; ++c) xrow[c] = 0;
  }
}

// ---------- weight prep: fp32 [K][N] -> bf16 transposed [N][Kpad] ----------
__global__ __launch_bounds__(256)
void prep_wt_all(const float* __restrict__ w1, const float* __restrict__ w2,
                 const float* __restrict__ w3, const float* __restrict__ w4,
                 const float* __restrict__ w5,
                 u16* __restrict__ wt1, u16* __restrict__ wt2, u16* __restrict__ wt3,
                 u16* __restrict__ wt4, u16* __restrict__ wt5)
{
  const int l = blockIdx.y;
  const float* w; u16* wt; int K, N, Kp;
  if (l == 0)      { w = w1; wt = wt1; K = 66;  N = 128; Kp = 96;  }
  else if (l == 1) { w = w2; wt = wt2; K = 128; N = 256; Kp = 128; }
  else if (l == 2) { w = w3; wt = wt3; K = 256; N = 512; Kp = 256; }
  else if (l == 3) { w = w4; wt = wt4; K = 512; N = 128; Kp = 512; }
  else             { w = w5; wt = wt5; K = 128; N = 64;  Kp = 128; }
  int i = blockIdx.x * 256 + threadIdx.x;
  if (i >= N * Kp) return;
  int n = i / Kp, kp = i - n * Kp;
  float v = (kp < K) ? w[(size_t)kp * N + n] : 0.0f;
  wt[i] = f2bf(v);
}

// ---------- GEMM (bf16 MFMA) + optional fused BN+ReLU on A + bias + stats ----------
// FUSE: A = raw Z_prev; y = relu(z*scA[k]+ttA[k]) applied during LDS staging.
template<int BN, bool FUSE>
__global__ __launch_bounds__(256)
void gemm_bn_kernel(const u16* __restrict__ X, int Kw,
                    const u16* __restrict__ WT,
                    const float* __restrict__ bias,
                    const float* __restrict__ psum, const float* __restrict__ psq,
                    const float* __restrict__ gw,   const float* __restrict__ bw,
                    u16* __restrict__ Z, int N,
                    float* __restrict__ csum, float* __restrict__ csq)
{
  constexpr int BM = 128;
  constexpr int AST = 40;                 // 32 data + 8 pad (bf16)
  __shared__ u16 Ash[BM * AST];
  __shared__ u16 Bsh[BN * AST];
  __shared__ float redS[4][128];
  __shared__ float redQ[4][128];
  __shared__ float scA[512];
  __shared__ float ttA[512];

  const int t = threadIdx.x;
  const int wave = t >> 6;
  const int lane = t & 63;
  const int lr = lane & 15;
  const int qd = lane >> 4;
  const int m0 = blockIdx.x * BM;
  const int n0 = blockIdx.y * BN;

  if (FUSE) {
    const float invB = 1.0f / 32768.0f;
    for (int c = t; c < Kw; c += 256) {
      float mean = psum[c] * invB;
      float var  = __fmaf_rn(-mean, mean, psq[c] * invB);  // biased
      float sc   = gw[c] * rsqrtf(var + EPS_BN);
      scA[c] = sc;
      ttA[c] = __fmaf_rn(-mean, sc, bw[c]);
    }
    __syncthreads();
  }

  f32x4 acc[2][BN / 16];
#pragma unroll
  for (int a = 0; a < 2; ++a)
#pragma unroll
    for (int b = 0; b < BN / 16; ++b) {
      acc[a][b][0] = 0.f; acc[a][b][1] = 0.f; acc[a][b][2] = 0.f; acc[a][b][3] = 0.f;
    }

  const int sr = t >> 2;          // 0..63
  const int sk = (t & 3) * 8;     // 0,8,16,24

  for (int k0 = 0; k0 < Kw; k0 += 32) {
#pragma unroll
    for (int rr = 0; rr < 2; ++rr) {
      int r = sr + rr * 64;
      uint4 g = *(const uint4*)(&X[(size_t)(m0 + r) * Kw + k0 + sk]);
      if (FUSE) {
        u32 w[4] = {g.x, g.y, g.z, g.w};
        u32 o[4];
#pragma unroll
        for (int e = 0; e < 4; ++e) {
          int kk = k0 + sk + 2 * e;
          float lo = bf2f((u16)(w[e] & 0xffffu));
          float hi = bf2f((u16)(w[e] >> 16));
          float yl = fmaxf(__fmaf_rn(lo, scA[kk],     ttA[kk]),     0.0f);
          float yh = fmaxf(__fmaf_rn(hi, scA[kk + 1], ttA[kk + 1]), 0.0f);
          o[e] = (u32)f2bf(yl) | ((u32)f2bf(yh) << 16);
        }
        g.x = o[0]; g.y = o[1]; g.z = o[2]; g.w = o[3];
      }
      *(uint4*)(&Ash[r * AST + sk]) = g;
    }
#pragma unroll
    for (int rr = 0; rr < BN / 64; ++rr) {
      int n = sr + rr * 64;
      *(uint4*)(&Bsh[n * AST + sk]) =
          *(const uint4*)(&WT[(size_t)(n0 + n) * Kw + k0 + sk]);
    }
    __syncthreads();
    bf16x8 af0 = *(const bf16x8*)(&Ash[(wave * 32 + lr) * AST + qd * 8]);
    bf16x8 af1 = *(const bf16x8*)(&Ash[(wave * 32 + 16 + lr) * AST + qd * 8]);
#pragma unroll
    for (int ct = 0; ct < BN / 16; ++ct) {
      bf16x8 bfr = *(const bf16x8*)(&Bsh[(ct * 16 + lr) * AST + qd * 8]);
      acc[0][ct] = __builtin_amdgcn_mfma_f32_16x16x32_bf16(af0, bfr, acc[0][ct], 0, 0, 0);
      acc[1][ct] = __builtin_amdgcn_mfma_f32_16x16x32_bf16(af1, bfr, acc[1][ct], 0, 0, 0);
    }
    __syncthreads();
  }

  // epilogue: bias, bf16 Z store, per-column partial sums
#pragma unroll
  for (int ct = 0; ct < BN / 16; ++ct) {
    int cg = n0 + ct * 16 + lr;
    float bv = bias[cg];
    float s = 0.f, sqv = 0.f;
#pragma unroll
    for (int rt = 0; rt < 2; ++rt) {
#pragma unroll
      for (int r = 0; r < 4; ++r) {
        float z = acc[rt][ct][r] + bv;
        int row = m0 + wave * 32 + rt * 16 + qd * 4 + r;  // C/D: row=quad*4+reg, col=lane&15
        Z[(size_t)row * N + cg] = f2bf(z);
        s += z;
        sqv = __fmaf_rn(z, z, sqv);
      }
    }
    s   += __shfl_xor(s, 16);   s   += __shfl_xor(s, 32);
    sqv += __shfl_xor(sqv, 16); sqv += __shfl_xor(sqv, 32);
    if (qd == 0) { redS[wave][ct * 16 + lr] = s; redQ[wave][ct * 16 + lr] = sqv; }
  }
  __syncthreads();
  if (t < BN) {
    float s  = redS[0][t] + redS[1][t] + redS[2][t] + redS[3][t];
    float sv = redQ[0][t] + redQ[1][t] + redQ[2][t] + redQ[3][t];
    atomicAdd(&csum[n0 + t], s);
    atomicAdd(&csq[n0 + t], sv);
  }
}

// ---------- final layer: fused BN5+ReLU + 64->2 GEMV, fp32 out ----------
__global__ __launch_bounds__(256)
void gemv6_kernel(const u16* __restrict__ Z5, const float* __restrict__ w6,
                  const float* __restrict__ b6,
                  const float* __restrict__ psum, const float* __restrict__ psq,
                  const float* __restrict__ gw,   const float* __restrict__ bw,
                  float* __restrict__ out)
{
  __shared__ float wsh[128];
  __shared__ float scs[64];
  __shared__ float tts[64];
  const int t = threadIdx.x;
  if (t < 128) wsh[t] = w6[t];
  if (t < 64) {
    const float invB = 1.0f / 32768.0f;
    float mean = psum[t] * invB;
    float var  = __fmaf_rn(-mean, mean, psq[t] * invB);
    float sc   = gw[t] * rsqrtf(var + EPS_BN);
    scs[t] = sc;
    tts[t] = __fmaf_rn(-mean, sc, bw[t]);
  }
  __syncthreads();
  const int q = blockIdx.x * 256 + t;
  const uint4* xv = (const uint4*)(Z5 + (size_t)q * 64);
  float a0 = 0.f, a1 = 0.f;
#pragma unroll
  for (int cc = 0; cc < 8; ++cc) {
    uint4 pk = xv[cc];
    u32 u[4] = {pk.x, pk.y, pk.z, pk.w};
#pragma unroll
    for (int uu = 0; uu < 4; ++uu) {
      int k = cc * 8 + uu * 2;
      float z0 = bf2f((u16)(u[uu] & 0xffffu));
      float z1 = bf2f((u16)(u[uu] >> 16));
      float x0 = fmaxf(__fmaf_rn(z0, scs[k],     tts[k]),     0.0f);
      float x1 = fmaxf(__fmaf_rn(z1, scs[k + 1], tts[k + 1]), 0.0f);
      x0 = bf2f(f2bf(x0));  // match prior bf16 round-trip of activations
      x1 = bf2f(f2bf(x1));
      a0 = __fmaf_rn(x0, wsh[2 * k + 0], a0);
      a1 = __fmaf_rn(x0, wsh[2 * k + 1], a1);
      a0 = __fmaf_rn(x1, wsh[2 * k + 2], a0);
      a1 = __fmaf_rn(x1, wsh[2 * k + 3], a1);
    }
  }
  float2 o; o.x = a0 + b6[0]; o.y = a1 + b6[1];
  ((float2*)out)[q] = o;
}

// ---------- launch ----------
extern "C" void kernel_launch(void* const* d_in, const int* in_sizes, int n_in,
                              void* d_out, int out_size, void* d_ws, size_t ws_size,
                              hipStream_t stream)
{
  const float2* pos = (const float2*)d_in[0];
  const float2* mc  = (const float2*)d_in[1];
  const float2* mv  = (const float2*)d_in[2];
  const float* w1 = (const float*)d_in[3];  const float* b1 = (const float*)d_in[4];
  const float* w2 = (const float*)d_in[5];  const float* b2 = (const float*)d_in[6];
  const float* w3 = (const float*)d_in[7];  const float* b3 = (const float*)d_in[8];
  const float* w4 = (const float*)d_in[9];  const float* b4 = (const float*)d_in[10];
  const float* w5 = (const float*)d_in[11]; const float* b5 = (const float*)d_in[12];
  const float* w6 = (const float*)d_in[13]; const float* b6 = (const float*)d_in[14];
  const float* g1 = (const float*)d_in[15]; const float* be1 = (const float*)d_in[16];
  const float* g2 = (const float*)d_in[17]; const float* be2 = (const float*)d_in[18];
  const float* g3 = (const float*)d_in[19]; const float* be3 = (const float*)d_in[20];
  const float* g4 = (const float*)d_in[21]; const float* be4 = (const float*)d_in[22];
  const float* g5 = (const float*)d_in[23]; const float* be5 = (const float*)d_in[24];

  // ws layout (bf16): X0 6.29MB | ZA 33.55MB | ZB 33.55MB | WT1..5 | stats
  char* ws = (char*)d_ws;
  u16* X0   = (u16*)(ws + 0);
  u16* ZA   = (u16*)(ws + 6291456);
  u16* ZB   = (u16*)(ws + 39845888);
  u16* WT1  = (u16*)(ws + 73400320);
  u16* WT2  = (u16*)(ws + 73424896);
  u16* WT3  = (u16*)(ws + 73490432);
  u16* WT4  = (u16*)(ws + 73752576);
  u16* WT5  = (u16*)(ws + 73883648);
  float* stats = (float*)(ws + 73900032);
  float* s1 = stats;        float* s2 = stats + 128;  float* s3 = stats + 384;
  float* s4 = stats + 896;  float* s5 = stats + 1024;
  float* sqb = stats + 1088;
  float* q1 = sqb;          float* q2 = sqb + 128;    float* q3 = sqb + 384;
  float* q4 = sqb + 896;    float* q5 = sqb + 1024;

  float* outX = (float*)d_out;
  float* outK = outX + 2 * B_ROWS;

  hipMemsetAsync(stats, 0, 2176 * sizeof(float), stream);
  prep_wt_all<<<dim3(512, 5), 256, 0, stream>>>(w1, w2, w3, w4, w5, WT1, WT2, WT3, WT4, WT5);
  knn_kernel<<<dim3(1024), 256, 0, stream>>>(pos, mc, mv, outK, X0);

  gemm_bn_kernel<128, false><<<dim3(256, 1), 256, 0, stream>>>(
      X0, 96, WT1, b1, nullptr, nullptr, nullptr, nullptr, ZA, 128, s1, q1);
  gemm_bn_kernel<128, true><<<dim3(256, 2), 256, 0, stream>>>(
      ZA, 128, WT2, b2, s1, q1, g1, be1, ZB, 256, s2, q2);
  gemm_bn_kernel<128, true><<<dim3(256, 4), 256, 0, stream>>>(
      ZB, 256, WT3, b3, s2, q2, g2, be2, ZA, 512, s3, q3);
  gemm_bn_kernel<128, true><<<dim3(256, 1), 256, 0, stream>>>(
      ZA, 512, WT4, b4, s3, q3, g3, be3, ZB, 128, s4, q4);
  gemm_bn_kernel<64, true><<<dim3(256, 1), 256, 0, stream>>>(
      ZB, 128, WT5, b5, s4, q4, g4, be4, ZA, 64, s5, q5);
  gemv6_kernel<<<dim3(128), 256, 0, stream>>>(ZA, w6, b6, s5, q5, g5, be5, outX);

  (void)in_sizes; (void)n_in; (void)out_size; (void)ws_size;
}